// Round 5
// baseline (359.803 us; speedup 1.0000x reference)
//
#include <hip/hip_runtime.h>
#include <hip/hip_bf16.h>
#include <cstdint>
#include <cstddef>

typedef __attribute__((ext_vector_type(8))) __bf16 bf16x8;
typedef __attribute__((ext_vector_type(4))) __bf16 bf16x4;
typedef __attribute__((ext_vector_type(4))) float  floatx4;

#define MFMA16x16x32(a, b, c) __builtin_amdgcn_mfma_f32_16x16x32_bf16((a), (b), (c), 0, 0, 0)

#define ATTN_SC 0.18033688011112042f  // (1/sqrt(64)) * log2(e), folded into Q projection

__device__ __forceinline__ void gload_lds16(const void* g, void* l) {
  __builtin_amdgcn_global_load_lds((const __attribute__((address_space(1))) void*)g,
                                   (__attribute__((address_space(3))) void*)l,
                                   16, 0, 0);
}

// ---------------- fused prep: weight casts + conv-weight pack + ktmp row0 + x cast ----------------

__global__ void prep_kernel(const float* __restrict__ x,
                            const float* __restrict__ Wq, const float* __restrict__ Wk,
                            const float* __restrict__ Wv, const float* __restrict__ Wo,
                            const float* __restrict__ Wconv,
                            __bf16* __restrict__ xb,
                            __bf16* __restrict__ wqb, __bf16* __restrict__ wkb,
                            __bf16* __restrict__ wvb, __bf16* __restrict__ wob,
                            __bf16* __restrict__ wc2, __bf16* __restrict__ ktmp) {
  const int bid = blockIdx.x, tid = threadIdx.x;
  if (bid < 4096) {
    const int which = bid >> 10;
    const float* src = (which == 0) ? Wq : (which == 1) ? Wk : (which == 2) ? Wv : Wo;
    __bf16* dst = (which == 0) ? wqb : (which == 1) ? wkb : (which == 2) ? wvb : wob;
    const int i = (bid & 1023) * 256 + tid;  // < 262144 quads
    floatx4 v = *(const floatx4*)(src + (size_t)i * 4);
    bf16x4 o; o[0] = (__bf16)v[0]; o[1] = (__bf16)v[1]; o[2] = (__bf16)v[2]; o[3] = (__bf16)v[3];
    *(bf16x4*)(dst + (size_t)i * 4) = o;
  } else if (bid < 5120) {
    const int t = (bid - 4096) * 256 + tid;  // < 262144
    const int o = t >> 8, c = t & 255;
    const float* base = Wconv + (size_t)o * 3072 + c * 12;
    float f[12];
    *(floatx4*)(f)     = *(const floatx4*)(base);
    *(floatx4*)(f + 4) = *(const floatx4*)(base + 4);
    *(floatx4*)(f + 8) = *(const floatx4*)(base + 8);
#pragma unroll
    for (int kw = 0; kw < 3; ++kw) {
      bf16x4 q;
#pragma unroll
      for (int j = 0; j < 4; ++j) q[j] = (__bf16)f[3 * j + kw];
      *(bf16x4*)(wc2 + (size_t)o * 3072 + kw * 1024 + c * 4) = q;
    }
  } else if (bid < 5136) {
    const int i = (bid - 5120) * 256 + tid;  // < 4096 : k_tmp[b,0,:] = x[b,0,:]
    const int b = i >> 10, c = i & 1023;
    ktmp[(size_t)b * 1025 * 1024 + c] = (__bf16)x[(size_t)b * 3072 * 1024 + c];
  } else {
    const int i = (bid - 5136) * 256 + tid;  // < 3145728 quads
    floatx4 v = *(const floatx4*)(x + (size_t)i * 4);
    bf16x4 o; o[0] = (__bf16)v[0]; o[1] = (__bf16)v[1]; o[2] = (__bf16)v[2]; o[3] = (__bf16)v[3];
    *(bf16x4*)(xb + (size_t)i * 4) = o;
  }
}

// V (b*1025+t, 1024) -> Vt[(b*16+h)*64 + d][t], t in [0,1024)
__global__ void vtrans_kernel(const __bf16* __restrict__ V, __bf16* __restrict__ Vt) {
  __shared__ __attribute__((aligned(16))) __bf16 tile[64][72];
  const int tid = threadIdx.x;
  const int bh = blockIdx.y;
  const int b = bh >> 4, h = bh & 15;
  const int t0 = blockIdx.x * 64;
  const int r = tid >> 3, s = tid & 7;
#pragma unroll
  for (int p = 0; p < 2; ++p) {
    const int t = p * 32 + r;
    bf16x8 v = *(const bf16x8*)(V + ((size_t)(b * 1025 + t0 + t)) * 1024 + h * 64 + s * 8);
    *(bf16x8*)(&tile[t][s * 8]) = v;
  }
  __syncthreads();
#pragma unroll
  for (int p = 0; p < 2; ++p) {
    const int d = p * 32 + r;
    bf16x8 o;
#pragma unroll
    for (int e = 0; e < 8; ++e) o[e] = tile[s * 8 + e][d];
    *(bf16x8*)(Vt + ((size_t)bh * 64 + d) * 1024 + t0 + s * 8) = o;
  }
}

// ---------------- pair-phase GEMM body: C[M,N] = A[M,K] @ Bw[N,K]^T ----------------
// BM=128, BN=256, K-pair=64 (2 half-K=32 subtiles). 6 half-K LDS slots = 3 pair
// buffers (144 KB). 512 threads = 8 waves (2M x 4N), per-wave 64x64.
// Chunk-XOR swizzle pc = c ^ (prow&7), conflict-free (verified r2).
// ONE barrier + ONE counted vmcnt per K-64 pair (sync frequency halved vs r3/r4):
//   pair t: STAGE(t+2) [6 DMAs, issued first; writes pair (t-1)%3, reads of which
//           retired before previous barrier]
//           16x ds_read (both halves; compiler tracks ds->MFMA deps)
//           32x MFMA
//           s_waitcnt vmcnt(6)  [certifies pair t+1, issued 2 pairs ago] + lgkmcnt(0)
//           s_barrier + sched_barrier(0)
// MODE 0: bf16 out. 1: bf16 out, conv row remap. 2: fp32 out + bias. 4: bf16 * ATTN_SC.

template <int MODE>
__device__ __forceinline__ void gemm8_body(
    const __bf16* __restrict__ A, const __bf16* __restrict__ Bw, void* __restrict__ Cout,
    const float* __restrict__ bias, int N, int K, int m0, int n0,
    __bf16* As, __bf16* Bs)
{
  const int tid  = threadIdx.x;
  const int wave = tid >> 6;
  const int lane = tid & 63;
  const int g    = lane >> 4;
  const int ln   = lane & 15;
  const int wr   = (wave >> 2) * 64;
  const int wc   = (wave & 3) * 64;

  // staging: thread writes linear LDS chunk tid (A) / tid, tid+512 (B);
  // source = inverse-swizzled logical element
  const int prow = tid >> 3;
  const int pc   = tid & 7;
  const int ca   = pc ^ (prow & 7);
  const size_t aSrc  = (size_t)(m0 + prow + ((ca >> 2) << 6)) * K + ((ca & 3) << 3);
  const size_t bSrc0 = (size_t)(n0 + prow + ((ca >> 2) << 7)) * K + ((ca & 3) << 3);
  const size_t bSrc1 = bSrc0 + (size_t)64 * K;

  // ds_read fragment element offsets (within a half-slot), swizzled
  int aOff[4], bOff[4];
#pragma unroll
  for (int i = 0; i < 4; ++i) {
    const int ra = wr + i * 16 + ln;
    const int pr = ra & 63;
    const int c  = ((ra >> 6) << 2) + g;
    aOff[i] = pr * 64 + ((c ^ (pr & 7)) << 3);
  }
#pragma unroll
  for (int j = 0; j < 4; ++j) {
    const int rb = wc + j * 16 + ln;
    const int pr = rb & 127;
    const int c  = ((rb >> 7) << 2) + g;
    bOff[j] = pr * 64 + ((c ^ (pr & 7)) << 3);
  }

  floatx4 acc[4][4];
#pragma unroll
  for (int i = 0; i < 4; ++i)
#pragma unroll
    for (int j = 0; j < 4; ++j) { floatx4 z = {0.f, 0.f, 0.f, 0.f}; acc[i][j] = z; }

  __bf16* const ad0 = As + (tid << 3);
  __bf16* const bd0 = Bs + (tid << 3);

  // stage pair t (halves 2t, 2t+1) into pair-slot t%3
  auto STAGE = [&](int t, int p) {
    const int koff = t * 64;
    __bf16* a0 = ad0 + (2 * p) * 4096;
    __bf16* b0 = bd0 + (2 * p) * 8192;
    gload_lds16(A  + aSrc  + koff,      a0);
    gload_lds16(Bw + bSrc0 + koff,      b0);
    gload_lds16(Bw + bSrc1 + koff,      b0 + 4096);
    gload_lds16(A  + aSrc  + koff + 32, a0 + 4096);
    gload_lds16(Bw + bSrc0 + koff + 32, b0 + 8192);
    gload_lds16(Bw + bSrc1 + koff + 32, b0 + 12288);
  };

  bf16x8 af0[4], bf0[4], af1[4], bf1[4];

#define READF(AF, BF, s)                                                           \
  {                                                                                \
    const __bf16* ah_ = As + (s) * 4096;                                           \
    const __bf16* bh_ = Bs + (s) * 8192;                                           \
    _Pragma("unroll")                                                              \
    for (int i_ = 0; i_ < 4; ++i_) AF[i_] = *(const bf16x8*)(ah_ + aOff[i_]);      \
    _Pragma("unroll")                                                              \
    for (int j_ = 0; j_ < 4; ++j_) BF[j_] = *(const bf16x8*)(bh_ + bOff[j_]);      \
  }

#define MFMAC(AF, BF)                                                              \
  {                                                                                \
    __builtin_amdgcn_s_setprio(1);                                                 \
    _Pragma("unroll")                                                              \
    for (int i_ = 0; i_ < 4; ++i_)                                                 \
      _Pragma("unroll")                                                            \
      for (int j_ = 0; j_ < 4; ++j_)                                               \
        acc[i_][j_] = MFMA16x16x32(AF[i_], BF[j_], acc[i_][j_]);                   \
    __builtin_amdgcn_s_setprio(0);                                                 \
  }

  const int NT = K >> 6;  // K-64 pairs: 48 (conv) or 16 (others); >= 2

  // prologue: 2 pairs in flight
  STAGE(0, 0);
  STAGE(1, 1);
  asm volatile("s_waitcnt vmcnt(6)" ::: "memory");  // pair 0 landed (wave-local)
  __builtin_amdgcn_s_barrier();                     // pair 0 landed (all waves)
  __builtin_amdgcn_sched_barrier(0);

  int p = 0;                                        // t % 3
  for (int t = 0; t < NT; ++t) {
    const int pn = (p + 2 >= 3) ? p - 1 : p + 2;    // (t+2) % 3
    if (t + 2 < NT) STAGE(t + 2, pn);
    READF(af0, bf0, 2 * p);
    READF(af1, bf1, 2 * p + 1);
    MFMAC(af0, bf0);
    MFMAC(af1, bf1);
    if (t + 2 < NT) {
      asm volatile("s_waitcnt vmcnt(6) lgkmcnt(0)" ::: "memory");  // pair t+1 landed
    } else if (t + 1 < NT) {
      asm volatile("s_waitcnt vmcnt(0) lgkmcnt(0)" ::: "memory");  // last pair landed
    }
    if (t + 1 < NT) {
      __builtin_amdgcn_s_barrier();
      __builtin_amdgcn_sched_barrier(0);
    }
    p = (p + 1 >= 3) ? 0 : p + 1;
  }

#undef READF
#undef MFMAC

  // ---- epilogue ----
#pragma unroll
  for (int j = 0; j < 4; ++j) {
    const int col = n0 + wc + j * 16 + ln;
    float bj = 0.f;
    if (MODE == 2) bj = bias[col];
#pragma unroll
    for (int i = 0; i < 4; ++i)
#pragma unroll
      for (int r = 0; r < 4; ++r) {
        const int row = m0 + wr + i * 16 + g * 4 + r;
        if (MODE == 2) {
          ((float*)Cout)[(size_t)row * N + col] = acc[i][j][r] + bj;
        } else if (MODE == 1) {
          const size_t orow = (size_t)(row >> 10) * 1025 + 1 + (row & 1023);
          ((__bf16*)Cout)[orow * 1024 + col] = (__bf16)acc[i][j][r];
        } else if (MODE == 4) {
          ((__bf16*)Cout)[(size_t)row * N + col] = (__bf16)(acc[i][j][r] * ATTN_SC);
        } else {
          ((__bf16*)Cout)[(size_t)row * N + col] = (__bf16)acc[i][j][r];
        }
      }
  }
}

// fused conv-GEMM (128 tiles, K=3072) + Q-GEMM (384 tiles, K=1024), XCD-grouped.
__global__ __launch_bounds__(512, 2) void gemm_convq_kernel(
    const __bf16* __restrict__ xb, const __bf16* __restrict__ wc2,
    const __bf16* __restrict__ wqb, __bf16* __restrict__ ktmp, __bf16* __restrict__ qb)
{
  __shared__ __attribute__((aligned(16))) __bf16 As[24576];   // 6 x 8 KB
  __shared__ __attribute__((aligned(16))) __bf16 Bs[49152];   // 6 x 16 KB
  const int xcd = blockIdx.x & 7, s = blockIdx.x >> 3;
  if (s < 16) {
    const int id = xcd * 16 + s;
    gemm8_body<1>(xb, wc2, ktmp, nullptr, 1024, 3072, (id >> 2) * 128, (id & 3) * 256, As, Bs);
  } else {
    const int id = xcd * 48 + (s - 16);
    gemm8_body<4>(xb, wqb, qb, nullptr, 1024, 1024, (id >> 2) * 128, (id & 3) * 256, As, Bs);
  }
}

// K + V projections: 33 row-tiles x 4 col-tiles x 2 proj = 264 blocks, XCD-grouped.
__global__ __launch_bounds__(512, 2) void gemm_kv_kernel(
    const __bf16* __restrict__ ktmp, const __bf16* __restrict__ wkb,
    const __bf16* __restrict__ wvb, __bf16* __restrict__ kb, __bf16* __restrict__ vb)
{
  __shared__ __attribute__((aligned(16))) __bf16 As[24576];
  __shared__ __attribute__((aligned(16))) __bf16 Bs[49152];
  const int id = (blockIdx.x & 7) * 33 + (blockIdx.x >> 3);
  const int p  = (id >= 132) ? 1 : 0;
  const int rest = id - p * 132;
  gemm8_body<0>(ktmp, p ? wvb : wkb, p ? vb : kb, nullptr, 1024, 1024,
                (rest >> 2) * 128, (rest & 3) * 256, As, Bs);
}

__global__ __launch_bounds__(512, 2) void gemm_o_kernel(
    const __bf16* __restrict__ ob, const __bf16* __restrict__ wob,
    float* __restrict__ out, const float* __restrict__ bo)
{
  __shared__ __attribute__((aligned(16))) __bf16 As[24576];
  __shared__ __attribute__((aligned(16))) __bf16 Bs[49152];
  const int id = (blockIdx.x & 7) * 48 + (blockIdx.x >> 3);
  gemm8_body<2>(ob, wob, out, bo, 1024, 1024, (id >> 2) * 128, (id & 3) * 256, As, Bs);
}

// ---------------- flash attention, cooperative LDS-staged double-buffered ----------------

__global__ __launch_bounds__(256) void attn_kernel(
    const __bf16* __restrict__ Q, const __bf16* __restrict__ Kk,
    const __bf16* __restrict__ Vt, __bf16* __restrict__ O)
{
  __shared__ __attribute__((aligned(16))) __bf16 Kd[2][64 * 64];  // [key][d]
  __shared__ __attribute__((aligned(16))) __bf16 Vd[2][64 * 64];  // [d][key]
  __shared__ __attribute__((aligned(16))) __bf16 Ps[4][32 * 64];

  const int tid  = threadIdx.x;
  const int wave = tid >> 6;
  const int lane = tid & 63;
  const int g    = lane >> 4;
  const int ln   = lane & 15;

  const int l    = blockIdx.x;
  const int xcd  = l & 7;
  const int b    = xcd >> 1;
  const int rest = l >> 3;
  const int h    = rest & 15;
  const int qt   = ((11 - (rest >> 4)) << 1) | (xcd & 1);  // heavy q-tiles dispatched first
  const int q0   = qt * 128 + wave * 32;

  const size_t qrow0 = (size_t)b * 3072 + q0;
  const size_t krow0 = (size_t)b * 1025;
  const size_t vtrow = ((size_t)(b * 16 + h)) * 64;
  const int hc = h * 64;
  const int sw = (ln & 7) << 3;
  __bf16* Pw = Ps[wave];

  // staging lane mapping: 4 DMAs/wave/tile; dst = uniform base + lane*16B
  const int srow = lane >> 3;          // row within 8-row DMA chunk
  const int scol = (lane & 7) * 8;     // col chunk (8 bf16 = 16 B)

  auto stage = [&](int kt, int bb) {
    const int kb0 = kt * 64;
#pragma unroll
    for (int i = 0; i < 2; ++i) {
      const int rr = (wave * 2 + i) * 8 + srow;   // tile row 0..63
      gload_lds16(Kk + (krow0 + kb0 + rr) * 1024 + hc + scol,
                  Kd[bb] + (size_t)rr * 64 + scol);
      gload_lds16(Vt + (vtrow + rr) * 1024 + kb0 + scol,
                  Vd[bb] + (size_t)rr * 64 + scol);
    }
  };

  // Q^T B-fragments (lane: q=16i+ln, d = kc*32+g*8+e), loop-invariant
  bf16x8 qf[2][2];
#pragma unroll
  for (int i = 0; i < 2; ++i)
#pragma unroll
    for (int kc = 0; kc < 2; ++kc)
      qf[i][kc] = *(const bf16x8*)(Q + (qrow0 + i * 16 + ln) * 1024 + hc + kc * 32 + g * 8);

  floatx4 oacc[2][4];  // [i][dt]: O^T[d=16dt+4g+r][q=16i+ln]
  floatx4 oal[2];      // l-sums via ones-MFMA: every lane's element = l[q=16i+ln]
#pragma unroll
  for (int i = 0; i < 2; ++i) {
    floatx4 z = {0.f, 0.f, 0.f, 0.f};
    oal[i] = z;
#pragma unroll
    for (int dt = 0; dt < 4; ++dt) oacc[i][dt] = z;
  }

  bf16x8 ones;
#pragma unroll
  for (int e = 0; e < 8; ++e) ones[e] = (__bf16)1.0f;

  // block-uniform depth (from heaviest row qt*128+127); per-wave mask start
  const int nkt_blk = (((qt * 128 + 127) / 3) >> 6) + 1;
  const int nfull   = (q0 >= 189) ? ((q0 - 189) / 192 + 1) : 0;  // this wave's unmasked tiles

  stage(0, 0);

  for (int kt = 0; kt < nkt_blk; ++kt) {
    const int bb = kt & 1;
    __syncthreads();                      // staging of kt complete; prior reads of buf bb done
    if (kt + 1 < nkt_blk) stage(kt + 1, bb ^ 1);
    const int kb0 = kt * 64;
    const bool masked = (kt >= nfull);

    // K A-fragments from LDS (b128)
    bf16x8 kf[4][2];
#pragma unroll
    for (int jk = 0; jk < 4; ++jk)
#pragma unroll
      for (int kc = 0; kc < 2; ++kc)
        kf[jk][kc] = *(const bf16x8*)(Kd[bb] + (jk * 16 + ln) * 64 + kc * 32 + g * 8);

    // S^T = K Q^T -> exp2 -> masked -> P^T into LDS (b64 swizzled writes)
#pragma unroll
    for (int jk = 0; jk < 4; ++jk)
#pragma unroll
      for (int i = 0; i < 2; ++i) {
        floatx4 s = {0.f, 0.f, 0.f, 0.f};
        s = MFMA16x16x32(kf[jk][0], qf[i][0], s);
        s = MFMA16x16x32(kf[jk][1], qf[i][1], s);
        float p[4];
#pragma unroll
        for (int r = 0; r < 4; ++r) {
          float e = __builtin_amdgcn_exp2f(s[r]);
          if (masked) {
            const int key = kb0 + jk * 16 + 4 * g + r;
            const int q   = q0 + i * 16 + ln;
            e = (3 * key <= q) ? e : 0.f;
          }
          p[r] = e;
        }
        bf16x4 pk;
        pk[0] = (__bf16)p[0]; pk[1] = (__bf16)p[1]; pk[2] = (__bf16)p[2]; pk[3] = (__bf16)p[3];
        *(bf16x4*)(Pw + (i * 16 + ln) * 64 + ((jk * 16 + 4 * g) ^ sw)) = pk;
      }

    // O^T += V^T P^T ; l += 1^T P^T   (V^T A-frags from dim-major LDS tile, b128)
#pragma unroll
    for (int kc = 0; kc < 2; ++kc) {
      bf16x8 pf0 = *(const bf16x8*)(Pw + (ln) * 64      + ((kc * 32 + g * 8) ^ sw));
      bf16x8 pf1 = *(const bf16x8*)(Pw + (16 + ln) * 64 + ((kc * 32 + g * 8) ^ sw));
      oal[0] = MFMA16x16x32(ones, pf0, oal[0]);
      oal[1] = MFMA16x16x32(ones, pf1, oal[1]);
#pragma unroll
      for (int dt = 0; dt < 4; ++dt) {
        bf16x8 vf = *(const bf16x8*)(Vd[bb] + (dt * 16 + ln) * 64 + kc * 32 + g * 8);
        oacc[0][dt] = MFMA16x16x32(vf, pf0, oacc[0][dt]);
        oacc[1][dt] = MFMA16x16x32(vf, pf1, oacc[1][dt]);
      }
    }
  }

  // epilogue: every lane already holds l for its q column (ones-MFMA); no shuffles
#pragma unroll
  for (int i = 0; i < 2; ++i) {
    const float inv = 1.0f / oal[i][0];
    const size_t row = qrow0 + i * 16 + ln;
#pragma unroll
    for (int dt = 0; dt < 4; ++dt) {
      bf16x4 o4;
#pragma unroll
      for (int r = 0; r < 4; ++r) o4[r] = (__bf16)(oacc[i][dt][r] * inv);
      *(bf16x4*)(O + row * 1024 + hc + dt * 16 + 4 * g) = o4;
    }
  }
}

// ---------------- host ----------------

extern "C" void kernel_launch(void* const* d_in, const int* in_sizes, int n_in,
                              void* d_out, int out_size, void* d_ws, size_t ws_size,
                              hipStream_t stream) {
  (void)in_sizes; (void)n_in; (void)out_size; (void)ws_size;
  const float* x     = (const float*)d_in[0];
  const float* Wq    = (const float*)d_in[1];
  const float* Wk    = (const float*)d_in[2];
  const float* Wv    = (const float*)d_in[3];
  const float* Wo    = (const float*)d_in[4];
  const float* bo    = (const float*)d_in[5];
  const float* Wconv = (const float*)d_in[6];

  char* ws = (char*)d_ws;
  const size_t SZ_XQ = (size_t)12288 * 1024 * 2;
  const size_t SZ_KT = (size_t)4224 * 1024 * 2;
  const size_t SZ_W  = (size_t)1024 * 1024 * 2;

  __bf16* xb   = (__bf16*)(ws);
  __bf16* qb   = (__bf16*)(ws + SZ_XQ);           // q proj (pre-scaled); attn output in-place
  __bf16* ktmp = (__bf16*)(ws + 2 * SZ_XQ);
  __bf16* kb   = (__bf16*)(ws + 2 * SZ_XQ + SZ_KT);
  __bf16* vb   = (__bf16*)(ws + 2 * SZ_XQ + 2 * SZ_KT);
  __bf16* wqb  = (__bf16*)(ws + 2 * SZ_XQ + 3 * SZ_KT);
  __bf16* wkb  = (__bf16*)(ws + 2 * SZ_XQ + 3 * SZ_KT + SZ_W);
  __bf16* wvb  = (__bf16*)(ws + 2 * SZ_XQ + 3 * SZ_KT + 2 * SZ_W);
  __bf16* wob  = (__bf16*)(ws + 2 * SZ_XQ + 3 * SZ_KT + 3 * SZ_W);
  __bf16* wc2  = (__bf16*)(ws + 2 * SZ_XQ + 3 * SZ_KT + 4 * SZ_W);
  __bf16* vt   = xb;  // xb dead after conv+q GEMMs; reuse for Vt (8.4 MB)

  prep_kernel<<<dim3(17424), dim3(256), 0, stream>>>(x, Wq, Wk, Wv, Wo, Wconv,
                                                     xb, wqb, wkb, wvb, wob, wc2, ktmp);
  gemm_convq_kernel<<<dim3(512), dim3(512), 0, stream>>>(xb, wc2, wqb, ktmp, qb);
  gemm_kv_kernel<<<dim3(264), dim3(512), 0, stream>>>(ktmp, wkb, wvb, kb, vb);
  vtrans_kernel<<<dim3(16, 64), dim3(256), 0, stream>>>(vb, vt);
  attn_kernel<<<dim3(1536), dim3(256), 0, stream>>>(qb, kb, vt, qb);
  gemm_o_kernel<<<dim3(384), dim3(512), 0, stream>>>(qb, wob, (float*)d_out, bo);
}

// Round 6
// 316.334 us; speedup vs baseline: 1.1374x; 1.1374x over previous
//
#include <hip/hip_runtime.h>
#include <hip/hip_bf16.h>
#include <cstdint>
#include <cstddef>

typedef __attribute__((ext_vector_type(8))) __bf16 bf16x8;
typedef __attribute__((ext_vector_type(4))) __bf16 bf16x4;
typedef __attribute__((ext_vector_type(4))) float  floatx4;

#define MFMA16x16x32(a, b, c) __builtin_amdgcn_mfma_f32_16x16x32_bf16((a), (b), (c), 0, 0, 0)

#define ATTN_SC 0.18033688011112042f  // (1/sqrt(64)) * log2(e), folded into Q projection

__device__ __forceinline__ void gload_lds16(const void* g, void* l) {
  __builtin_amdgcn_global_load_lds((const __attribute__((address_space(1))) void*)g,
                                   (__attribute__((address_space(3))) void*)l,
                                   16, 0, 0);
}

// ---------------- fused prep: weight casts + conv-weight pack + ktmp row0 + x cast ----------------

__global__ void prep_kernel(const float* __restrict__ x,
                            const float* __restrict__ Wq, const float* __restrict__ Wk,
                            const float* __restrict__ Wv, const float* __restrict__ Wo,
                            const float* __restrict__ Wconv,
                            __bf16* __restrict__ xb,
                            __bf16* __restrict__ wqb, __bf16* __restrict__ wkb,
                            __bf16* __restrict__ wvb, __bf16* __restrict__ wob,
                            __bf16* __restrict__ wc2, __bf16* __restrict__ ktmp) {
  const int bid = blockIdx.x, tid = threadIdx.x;
  if (bid < 4096) {
    const int which = bid >> 10;
    const float* src = (which == 0) ? Wq : (which == 1) ? Wk : (which == 2) ? Wv : Wo;
    __bf16* dst = (which == 0) ? wqb : (which == 1) ? wkb : (which == 2) ? wvb : wob;
    const int i = (bid & 1023) * 256 + tid;  // < 262144 quads
    floatx4 v = *(const floatx4*)(src + (size_t)i * 4);
    bf16x4 o; o[0] = (__bf16)v[0]; o[1] = (__bf16)v[1]; o[2] = (__bf16)v[2]; o[3] = (__bf16)v[3];
    *(bf16x4*)(dst + (size_t)i * 4) = o;
  } else if (bid < 5120) {
    const int t = (bid - 4096) * 256 + tid;  // < 262144
    const int o = t >> 8, c = t & 255;
    const float* base = Wconv + (size_t)o * 3072 + c * 12;
    float f[12];
    *(floatx4*)(f)     = *(const floatx4*)(base);
    *(floatx4*)(f + 4) = *(const floatx4*)(base + 4);
    *(floatx4*)(f + 8) = *(const floatx4*)(base + 8);
#pragma unroll
    for (int kw = 0; kw < 3; ++kw) {
      bf16x4 q;
#pragma unroll
      for (int j = 0; j < 4; ++j) q[j] = (__bf16)f[3 * j + kw];
      *(bf16x4*)(wc2 + (size_t)o * 3072 + kw * 1024 + c * 4) = q;
    }
  } else if (bid < 5136) {
    const int i = (bid - 5120) * 256 + tid;  // < 4096 : k_tmp[b,0,:] = x[b,0,:]
    const int b = i >> 10, c = i & 1023;
    ktmp[(size_t)b * 1025 * 1024 + c] = (__bf16)x[(size_t)b * 3072 * 1024 + c];
  } else {
    const int i = (bid - 5136) * 256 + tid;  // < 3145728 quads
    floatx4 v = *(const floatx4*)(x + (size_t)i * 4);
    bf16x4 o; o[0] = (__bf16)v[0]; o[1] = (__bf16)v[1]; o[2] = (__bf16)v[2]; o[3] = (__bf16)v[3];
    *(bf16x4*)(xb + (size_t)i * 4) = o;
  }
}

// V (b*1025+t, 1024) -> Vt[(b*16+h)*64 + d][t], t in [0,1024)
__global__ void vtrans_kernel(const __bf16* __restrict__ V, __bf16* __restrict__ Vt) {
  __shared__ __attribute__((aligned(16))) __bf16 tile[64][72];
  const int tid = threadIdx.x;
  const int bh = blockIdx.y;
  const int b = bh >> 4, h = bh & 15;
  const int t0 = blockIdx.x * 64;
  const int r = tid >> 3, s = tid & 7;
#pragma unroll
  for (int p = 0; p < 2; ++p) {
    const int t = p * 32 + r;
    bf16x8 v = *(const bf16x8*)(V + ((size_t)(b * 1025 + t0 + t)) * 1024 + h * 64 + s * 8);
    *(bf16x8*)(&tile[t][s * 8]) = v;
  }
  __syncthreads();
#pragma unroll
  for (int p = 0; p < 2; ++p) {
    const int d = p * 32 + r;
    bf16x8 o;
#pragma unroll
    for (int e = 0; e < 8; ++e) o[e] = tile[s * 8 + e][d];
    *(bf16x8*)(Vt + ((size_t)bh * 64 + d) * 1024 + t0 + s * 8) = o;
  }
}

// ---------------- pipelined GEMM body: C[M,N] = A[M,K] @ Bw[N,K]^T ----------------
// BM=128, BN=256, half-K=32. THREE half-K LDS slots (72 KB/block) -> 2 blocks/CU
// (cross-block overlap hides LDS-port + sync serialization; the r1-r5 96-144 KB
// variants ran 1 block/CU and all plateaued at ~71 us regardless of schedule).
// 512 threads = 8 waves (2M x 4N), per-wave 64x64. Chunk-XOR swizzle pc = c ^ (prow&7),
// conflict-free (verified r2). Depth-2 prefetch, counted vmcnt (never 0 in steady state):
//   phase h: READF(slot h%3) -> STAGE(h+2 into slot (h-1)%3; WAR: its reads retired
//            before previous barrier) -> 16x MFMA -> vmcnt(3)[h+1 landed]+lgkmcnt(0)
//            -> s_barrier + sched_barrier(0)
// MODE 0: bf16 out. 1: bf16 out, conv row remap. 2: fp32 out + bias. 4: bf16 * ATTN_SC.

template <int MODE>
__device__ __forceinline__ void gemm8_body(
    const __bf16* __restrict__ A, const __bf16* __restrict__ Bw, void* __restrict__ Cout,
    const float* __restrict__ bias, int N, int K, int m0, int n0,
    __bf16* As, __bf16* Bs)
{
  const int tid  = threadIdx.x;
  const int wave = tid >> 6;
  const int lane = tid & 63;
  const int g    = lane >> 4;
  const int ln   = lane & 15;
  const int wr   = (wave >> 2) * 64;
  const int wc   = (wave & 3) * 64;

  // staging: thread writes linear LDS chunk tid (A) / tid, tid+512 (B);
  // source = inverse-swizzled logical element
  const int prow = tid >> 3;
  const int pc   = tid & 7;
  const int ca   = pc ^ (prow & 7);
  const size_t aSrc  = (size_t)(m0 + prow + ((ca >> 2) << 6)) * K + ((ca & 3) << 3);
  const size_t bSrc0 = (size_t)(n0 + prow + ((ca >> 2) << 7)) * K + ((ca & 3) << 3);
  const size_t bSrc1 = bSrc0 + (size_t)64 * K;

  // ds_read fragment element offsets (within a half-slot), swizzled
  int aOff[4], bOff[4];
#pragma unroll
  for (int i = 0; i < 4; ++i) {
    const int ra = wr + i * 16 + ln;
    const int pr = ra & 63;
    const int c  = ((ra >> 6) << 2) + g;
    aOff[i] = pr * 64 + ((c ^ (pr & 7)) << 3);
  }
#pragma unroll
  for (int j = 0; j < 4; ++j) {
    const int rb = wc + j * 16 + ln;
    const int pr = rb & 127;
    const int c  = ((rb >> 7) << 2) + g;
    bOff[j] = pr * 64 + ((c ^ (pr & 7)) << 3);
  }

  floatx4 acc[4][4];
#pragma unroll
  for (int i = 0; i < 4; ++i)
#pragma unroll
    for (int j = 0; j < 4; ++j) { floatx4 z = {0.f, 0.f, 0.f, 0.f}; acc[i][j] = z; }

  __bf16* const ad0 = As + (tid << 3);
  __bf16* const bd0 = Bs + (tid << 3);

  // stage half t (K offset t*32) into half-slot s (0..2)
  auto STAGE = [&](int t, int s) {
    const int koff = t * 32;
    gload_lds16(A  + aSrc  + koff, ad0 + s * 4096);
    gload_lds16(Bw + bSrc0 + koff, bd0 + s * 8192);
    gload_lds16(Bw + bSrc1 + koff, bd0 + s * 8192 + 4096);
  };

  bf16x8 af[4], bf[4];

#define READF(s)                                                                   \
  {                                                                                \
    const __bf16* ah_ = As + (s) * 4096;                                           \
    const __bf16* bh_ = Bs + (s) * 8192;                                           \
    _Pragma("unroll")                                                              \
    for (int i_ = 0; i_ < 4; ++i_) af[i_] = *(const bf16x8*)(ah_ + aOff[i_]);      \
    _Pragma("unroll")                                                              \
    for (int j_ = 0; j_ < 4; ++j_) bf[j_] = *(const bf16x8*)(bh_ + bOff[j_]);      \
  }

#define MFMAC()                                                                    \
  {                                                                                \
    __builtin_amdgcn_s_setprio(1);                                                 \
    _Pragma("unroll")                                                              \
    for (int i_ = 0; i_ < 4; ++i_)                                                 \
      _Pragma("unroll")                                                            \
      for (int j_ = 0; j_ < 4; ++j_)                                               \
        acc[i_][j_] = MFMA16x16x32(af[i_], bf[j_], acc[i_][j_]);                   \
    __builtin_amdgcn_s_setprio(0);                                                 \
  }

  const int HT = K >> 5;  // K-halves: 96 (conv) or 32 (others)

  // prologue: 2 halves in flight
  STAGE(0, 0);
  STAGE(1, 1);
  asm volatile("s_waitcnt vmcnt(3)" ::: "memory");  // half 0 landed (wave-local)
  __builtin_amdgcn_s_barrier();                     // half 0 landed (all waves)
  __builtin_amdgcn_sched_barrier(0);

  int sp = 0;  // slot of phase h
  for (int h = 0; h < HT; ++h) {
    const int s2 = (sp + 2 >= 3) ? sp - 1 : sp + 2;  // slot of h+2 == slot of h-1
    READF(sp);
    if (h + 2 < HT) STAGE(h + 2, s2);
    MFMAC();
    if (h + 1 < HT) {
      if (h + 2 < HT) { asm volatile("s_waitcnt vmcnt(3) lgkmcnt(0)" ::: "memory"); }
      else            { asm volatile("s_waitcnt vmcnt(0) lgkmcnt(0)" ::: "memory"); }
      __builtin_amdgcn_s_barrier();
      __builtin_amdgcn_sched_barrier(0);
    }
    sp = (sp + 1 >= 3) ? 0 : sp + 1;
  }

#undef READF
#undef MFMAC

  // ---- epilogue ----
#pragma unroll
  for (int j = 0; j < 4; ++j) {
    const int col = n0 + wc + j * 16 + ln;
    float bj = 0.f;
    if (MODE == 2) bj = bias[col];
#pragma unroll
    for (int i = 0; i < 4; ++i)
#pragma unroll
      for (int r = 0; r < 4; ++r) {
        const int row = m0 + wr + i * 16 + g * 4 + r;
        if (MODE == 2) {
          ((float*)Cout)[(size_t)row * N + col] = acc[i][j][r] + bj;
        } else if (MODE == 1) {
          const size_t orow = (size_t)(row >> 10) * 1025 + 1 + (row & 1023);
          ((__bf16*)Cout)[orow * 1024 + col] = (__bf16)acc[i][j][r];
        } else if (MODE == 4) {
          ((__bf16*)Cout)[(size_t)row * N + col] = (__bf16)(acc[i][j][r] * ATTN_SC);
        } else {
          ((__bf16*)Cout)[(size_t)row * N + col] = (__bf16)acc[i][j][r];
        }
      }
  }
}

// fused conv-GEMM (128 tiles, K=3072) + Q-GEMM (384 tiles, K=1024), XCD-grouped.
__global__ __launch_bounds__(512, 4) void gemm_convq_kernel(
    const __bf16* __restrict__ xb, const __bf16* __restrict__ wc2,
    const __bf16* __restrict__ wqb, __bf16* __restrict__ ktmp, __bf16* __restrict__ qb)
{
  __shared__ __attribute__((aligned(16))) __bf16 As[12288];   // 3 x 8 KB
  __shared__ __attribute__((aligned(16))) __bf16 Bs[24576];   // 3 x 16 KB
  const int xcd = blockIdx.x & 7, s = blockIdx.x >> 3;
  if (s < 16) {
    const int id = xcd * 16 + s;
    gemm8_body<1>(xb, wc2, ktmp, nullptr, 1024, 3072, (id >> 2) * 128, (id & 3) * 256, As, Bs);
  } else {
    const int id = xcd * 48 + (s - 16);
    gemm8_body<4>(xb, wqb, qb, nullptr, 1024, 1024, (id >> 2) * 128, (id & 3) * 256, As, Bs);
  }
}

// K + V projections: 33 row-tiles x 4 col-tiles x 2 proj = 264 blocks, XCD-grouped.
__global__ __launch_bounds__(512, 4) void gemm_kv_kernel(
    const __bf16* __restrict__ ktmp, const __bf16* __restrict__ wkb,
    const __bf16* __restrict__ wvb, __bf16* __restrict__ kb, __bf16* __restrict__ vb)
{
  __shared__ __attribute__((aligned(16))) __bf16 As[12288];
  __shared__ __attribute__((aligned(16))) __bf16 Bs[24576];
  const int id = (blockIdx.x & 7) * 33 + (blockIdx.x >> 3);
  const int p  = (id >= 132) ? 1 : 0;
  const int rest = id - p * 132;
  gemm8_body<0>(ktmp, p ? wvb : wkb, p ? vb : kb, nullptr, 1024, 1024,
                (rest >> 2) * 128, (rest & 3) * 256, As, Bs);
}

__global__ __launch_bounds__(512, 4) void gemm_o_kernel(
    const __bf16* __restrict__ ob, const __bf16* __restrict__ wob,
    float* __restrict__ out, const float* __restrict__ bo)
{
  __shared__ __attribute__((aligned(16))) __bf16 As[12288];
  __shared__ __attribute__((aligned(16))) __bf16 Bs[24576];
  const int id = (blockIdx.x & 7) * 48 + (blockIdx.x >> 3);
  gemm8_body<2>(ob, wob, out, bo, 1024, 1024, (id >> 2) * 128, (id & 3) * 256, As, Bs);
}

// ---------------- flash attention, cooperative LDS-staged double-buffered ----------------

__global__ __launch_bounds__(256) void attn_kernel(
    const __bf16* __restrict__ Q, const __bf16* __restrict__ Kk,
    const __bf16* __restrict__ Vt, __bf16* __restrict__ O)
{
  __shared__ __attribute__((aligned(16))) __bf16 Kd[2][64 * 64];  // [key][d]
  __shared__ __attribute__((aligned(16))) __bf16 Vd[2][64 * 64];  // [d][key]
  __shared__ __attribute__((aligned(16))) __bf16 Ps[4][32 * 64];

  const int tid  = threadIdx.x;
  const int wave = tid >> 6;
  const int lane = tid & 63;
  const int g    = lane >> 4;
  const int ln   = lane & 15;

  const int l    = blockIdx.x;
  const int xcd  = l & 7;
  const int b    = xcd >> 1;
  const int rest = l >> 3;
  const int h    = rest & 15;
  const int qt   = ((11 - (rest >> 4)) << 1) | (xcd & 1);  // heavy q-tiles dispatched first
  const int q0   = qt * 128 + wave * 32;

  const size_t qrow0 = (size_t)b * 3072 + q0;
  const size_t krow0 = (size_t)b * 1025;
  const size_t vtrow = ((size_t)(b * 16 + h)) * 64;
  const int hc = h * 64;
  const int sw = (ln & 7) << 3;
  __bf16* Pw = Ps[wave];

  // staging lane mapping: 4 DMAs/wave/tile; dst = uniform base + lane*16B
  const int srow = lane >> 3;          // row within 8-row DMA chunk
  const int scol = (lane & 7) * 8;     // col chunk (8 bf16 = 16 B)

  auto stage = [&](int kt, int bb) {
    const int kb0 = kt * 64;
#pragma unroll
    for (int i = 0; i < 2; ++i) {
      const int rr = (wave * 2 + i) * 8 + srow;   // tile row 0..63
      gload_lds16(Kk + (krow0 + kb0 + rr) * 1024 + hc + scol,
                  Kd[bb] + (size_t)rr * 64 + scol);
      gload_lds16(Vt + (vtrow + rr) * 1024 + kb0 + scol,
                  Vd[bb] + (size_t)rr * 64 + scol);
    }
  };

  // Q^T B-fragments (lane: q=16i+ln, d = kc*32+g*8+e), loop-invariant
  bf16x8 qf[2][2];
#pragma unroll
  for (int i = 0; i < 2; ++i)
#pragma unroll
    for (int kc = 0; kc < 2; ++kc)
      qf[i][kc] = *(const bf16x8*)(Q + (qrow0 + i * 16 + ln) * 1024 + hc + kc * 32 + g * 8);

  floatx4 oacc[2][4];  // [i][dt]: O^T[d=16dt+4g+r][q=16i+ln]
  floatx4 oal[2];      // l-sums via ones-MFMA: every lane's element = l[q=16i+ln]
#pragma unroll
  for (int i = 0; i < 2; ++i) {
    floatx4 z = {0.f, 0.f, 0.f, 0.f};
    oal[i] = z;
#pragma unroll
    for (int dt = 0; dt < 4; ++dt) oacc[i][dt] = z;
  }

  bf16x8 ones;
#pragma unroll
  for (int e = 0; e < 8; ++e) ones[e] = (__bf16)1.0f;

  // block-uniform depth (from heaviest row qt*128+127); per-wave mask start
  const int nkt_blk = (((qt * 128 + 127) / 3) >> 6) + 1;
  const int nfull   = (q0 >= 189) ? ((q0 - 189) / 192 + 1) : 0;  // this wave's unmasked tiles

  stage(0, 0);

  for (int kt = 0; kt < nkt_blk; ++kt) {
    const int bb = kt & 1;
    __syncthreads();                      // staging of kt complete; prior reads of buf bb done
    if (kt + 1 < nkt_blk) stage(kt + 1, bb ^ 1);
    const int kb0 = kt * 64;
    const bool masked = (kt >= nfull);

    // K A-fragments from LDS (b128)
    bf16x8 kf[4][2];
#pragma unroll
    for (int jk = 0; jk < 4; ++jk)
#pragma unroll
      for (int kc = 0; kc < 2; ++kc)
        kf[jk][kc] = *(const bf16x8*)(Kd[bb] + (jk * 16 + ln) * 64 + kc * 32 + g * 8);

    // S^T = K Q^T -> exp2 -> masked -> P^T into LDS (b64 swizzled writes)
#pragma unroll
    for (int jk = 0; jk < 4; ++jk)
#pragma unroll
      for (int i = 0; i < 2; ++i) {
        floatx4 s = {0.f, 0.f, 0.f, 0.f};
        s = MFMA16x16x32(kf[jk][0], qf[i][0], s);
        s = MFMA16x16x32(kf[jk][1], qf[i][1], s);
        float p[4];
#pragma unroll
        for (int r = 0; r < 4; ++r) {
          float e = __builtin_amdgcn_exp2f(s[r]);
          if (masked) {
            const int key = kb0 + jk * 16 + 4 * g + r;
            const int q   = q0 + i * 16 + ln;
            e = (3 * key <= q) ? e : 0.f;
          }
          p[r] = e;
        }
        bf16x4 pk;
        pk[0] = (__bf16)p[0]; pk[1] = (__bf16)p[1]; pk[2] = (__bf16)p[2]; pk[3] = (__bf16)p[3];
        *(bf16x4*)(Pw + (i * 16 + ln) * 64 + ((jk * 16 + 4 * g) ^ sw)) = pk;
      }

    // O^T += V^T P^T ; l += 1^T P^T   (V^T A-frags from dim-major LDS tile, b128)
#pragma unroll
    for (int kc = 0; kc < 2; ++kc) {
      bf16x8 pf0 = *(const bf16x8*)(Pw + (ln) * 64      + ((kc * 32 + g * 8) ^ sw));
      bf16x8 pf1 = *(const bf16x8*)(Pw + (16 + ln) * 64 + ((kc * 32 + g * 8) ^ sw));
      oal[0] = MFMA16x16x32(ones, pf0, oal[0]);
      oal[1] = MFMA16x16x32(ones, pf1, oal[1]);
#pragma unroll
      for (int dt = 0; dt < 4; ++dt) {
        bf16x8 vf = *(const bf16x8*)(Vd[bb] + (dt * 16 + ln) * 64 + kc * 32 + g * 8);
        oacc[0][dt] = MFMA16x16x32(vf, pf0, oacc[0][dt]);
        oacc[1][dt] = MFMA16x16x32(vf, pf1, oacc[1][dt]);
      }
    }
  }

  // epilogue: every lane already holds l for its q column (ones-MFMA); no shuffles
#pragma unroll
  for (int i = 0; i < 2; ++i) {
    const float inv = 1.0f / oal[i][0];
    const size_t row = qrow0 + i * 16 + ln;
#pragma unroll
    for (int dt = 0; dt < 4; ++dt) {
      bf16x4 o4;
#pragma unroll
      for (int r = 0; r < 4; ++r) o4[r] = (__bf16)(oacc[i][dt][r] * inv);
      *(bf16x4*)(O + row * 1024 + hc + dt * 16 + 4 * g) = o4;
    }
  }
}

// ---------------- host ----------------

extern "C" void kernel_launch(void* const* d_in, const int* in_sizes, int n_in,
                              void* d_out, int out_size, void* d_ws, size_t ws_size,
                              hipStream_t stream) {
  (void)in_sizes; (void)n_in; (void)out_size; (void)ws_size;
  const float* x     = (const float*)d_in[0];
  const float* Wq    = (const float*)d_in[1];
  const float* Wk    = (const float*)d_in[2];
  const float* Wv    = (const float*)d_in[3];
  const float* Wo    = (const float*)d_in[4];
  const float* bo    = (const float*)d_in[5];
  const float* Wconv = (const float*)d_in[6];

  char* ws = (char*)d_ws;
  const size_t SZ_XQ = (size_t)12288 * 1024 * 2;
  const size_t SZ_KT = (size_t)4224 * 1024 * 2;
  const size_t SZ_W  = (size_t)1024 * 1024 * 2;

  __bf16* xb   = (__bf16*)(ws);
  __bf16* qb   = (__bf16*)(ws + SZ_XQ);           // q proj (pre-scaled); attn output in-place
  __bf16* ktmp = (__bf16*)(ws + 2 * SZ_XQ);
  __bf16* kb   = (__bf16*)(ws + 2 * SZ_XQ + SZ_KT);
  __bf16* vb   = (__bf16*)(ws + 2 * SZ_XQ + 2 * SZ_KT);
  __bf16* wqb  = (__bf16*)(ws + 2 * SZ_XQ + 3 * SZ_KT);
  __bf16* wkb  = (__bf16*)(ws + 2 * SZ_XQ + 3 * SZ_KT + SZ_W);
  __bf16* wvb  = (__bf16*)(ws + 2 * SZ_XQ + 3 * SZ_KT + 2 * SZ_W);
  __bf16* wob  = (__bf16*)(ws + 2 * SZ_XQ + 3 * SZ_KT + 3 * SZ_W);
  __bf16* wc2  = (__bf16*)(ws + 2 * SZ_XQ + 3 * SZ_KT + 4 * SZ_W);
  __bf16* vt   = xb;  // xb dead after conv+q GEMMs; reuse for Vt (8.4 MB)

  prep_kernel<<<dim3(17424), dim3(256), 0, stream>>>(x, Wq, Wk, Wv, Wo, Wconv,
                                                     xb, wqb, wkb, wvb, wob, wc2, ktmp);
  gemm_convq_kernel<<<dim3(512), dim3(512), 0, stream>>>(xb, wc2, wqb, ktmp, qb);
  gemm_kv_kernel<<<dim3(264), dim3(512), 0, stream>>>(ktmp, wkb, wvb, kb, vb);
  vtrans_kernel<<<dim3(16, 64), dim3(256), 0, stream>>>(vb, vt);
  attn_kernel<<<dim3(1536), dim3(256), 0, stream>>>(qb, kb, vt, qb);
  gemm_o_kernel<<<dim3(384), dim3(512), 0, stream>>>(qb, wob, (float*)d_out, bo);
}